// Round 16
// baseline (554.090 us; speedup 1.0000x reference)
//
#include <hip/hip_runtime.h>
#include <hip/hip_bf16.h>
#include <cstddef>

#define NA 50000
#define NP 100000
#define NE 200000
#define SCAN_CHUNK 1024

typedef unsigned short u16;
typedef unsigned int u32;
typedef short v8s __attribute__((ext_vector_type(8)));
typedef float f32x4 __attribute__((ext_vector_type(4)));

__device__ __forceinline__ float elu_f(float x) {
  return x > 0.0f ? x : expm1f(x);
}
__device__ __forceinline__ u16 f2bf(float x) {
  u32 u = __float_as_uint(x);
  return (u16)((u + 0x7fffu + ((u >> 16) & 1u)) >> 16);
}
__device__ __forceinline__ float bf2f(u16 h) {
  return __uint_as_float(((u32)h) << 16);
}
__device__ __forceinline__ u32 pk2(float a, float b) {
  return (u32)f2bf(a) | ((u32)f2bf(b) << 16);
}
__device__ __forceinline__ float lo_f(u32 w) { return __uint_as_float(w << 16); }
__device__ __forceinline__ float hi_f(u32 w) { return __uint_as_float(w & 0xffff0000u); }

// async global->LDS, 16B per lane; ldst must be wave-uniform (HW adds lane*16)
__device__ __forceinline__ void gload_lds16(const u16* gsrc, u16* ldst) {
  __builtin_amdgcn_global_load_lds(
      (const __attribute__((address_space(1))) u32*)gsrc,
      (__attribute__((address_space(3))) u32*)ldst, 16, 0, 0);
}

// ---------------- degree counting (int) ----------------
__global__ void count_deg_i(const int* __restrict__ dst_p, const int* __restrict__ dst_a,
                            int* cnt_p, int* cnt_a) {
  int i = blockIdx.x * blockDim.x + threadIdx.x;
  if (i < NE) atomicAdd(&cnt_p[dst_p[i]], 1);
  else if (i < 2 * NE) atomicAdd(&cnt_a[dst_a[i - NE]], 1);
}

// ---------------- 3-kernel exclusive scan ----------------
__global__ void block_sums_k(const int* __restrict__ cnt, int* __restrict__ bsums, int n) {
  __shared__ int red[256];
  int t = threadIdx.x;
  int base = blockIdx.x * SCAN_CHUNK + t * 4;
  int s = 0;
  #pragma unroll
  for (int i = 0; i < 4; ++i) {
    int idx = base + i;
    if (idx < n) s += cnt[idx];
  }
  red[t] = s;
  __syncthreads();
  for (int off = 128; off > 0; off >>= 1) {
    if (t < off) red[t] += red[t + off];
    __syncthreads();
  }
  if (t == 0) bsums[blockIdx.x] = red[0];
}

__global__ void scan_bsums_k(int* bsums, int nb) {  // nb <= 256, single block
  __shared__ int tmp[256];
  int t = threadIdx.x;
  int orig = (t < nb) ? bsums[t] : 0;
  tmp[t] = orig;
  __syncthreads();
  for (int off = 1; off < 256; off <<= 1) {
    int u = (t >= off) ? tmp[t - off] : 0;
    __syncthreads();
    tmp[t] += u;
    __syncthreads();
  }
  if (t < nb) bsums[t] = tmp[t] - orig;  // exclusive
}

// writes row_start AND cursor copy
__global__ void scan_final_k(const int* __restrict__ cnt, const int* __restrict__ bsums,
                             int* __restrict__ row_start, int* __restrict__ cursor,
                             int n, int total) {
  __shared__ int red[256];
  int t = threadIdx.x;
  int base = blockIdx.x * SCAN_CHUNK + t * 4;
  int v[4];
  int s = 0;
  #pragma unroll
  for (int i = 0; i < 4; ++i) {
    int idx = base + i;
    v[i] = (idx < n) ? cnt[idx] : 0;
    s += v[i];
  }
  int orig = s;
  red[t] = s;
  __syncthreads();
  for (int off = 1; off < 256; off <<= 1) {
    int u = (t >= off) ? red[t - off] : 0;
    __syncthreads();
    red[t] += u;
    __syncthreads();
  }
  int excl = red[t] - orig + bsums[blockIdx.x];
  #pragma unroll
  for (int i = 0; i < 4; ++i) {
    int idx = base + i;
    if (idx < n) {
      row_start[idx] = excl;
      cursor[idx] = excl;
    }
    excl += v[i];
  }
  if (blockIdx.x == 0 && t == 0) row_start[n] = total;
}

__global__ void csr_fill(const int* __restrict__ src, const int* __restrict__ dst,
                         int* cursor, int* __restrict__ csr_src) {
  int e = blockIdx.x * blockDim.x + threadIdx.x;
  if (e < NE) {
    int p = atomicAdd(&cursor[dst[e]], 1);
    csr_src[p] = src[e];
  }
}

// ---------------- f32 -> bf16 bulk convert ----------------
__global__ void to_bf16(const float* __restrict__ in, u16* __restrict__ out, int n4) {
  int i = blockIdx.x * 256 + threadIdx.x;
  if (i >= n4) return;
  float4 v = ((const float4*)in)[i];
  uint2 o;
  o.x = pk2(v.x, v.y);
  o.y = pk2(v.z, v.w);
  *(uint2*)(out + (size_t)i * 4) = o;
}

// ---------------- weight pack (all matrices, one launch) ----------------
// W: [256][K] f32 -> Wp[ks][c 16][lane 64][8] bf16  (16 KB per 32-K chunk)
struct PackJobs {
  const float* src[12];
  u16* dst[12];
  int K[12];
  int boff[13];
};

__global__ void pack_all(PackJobs J) {
  int blk = blockIdx.x;
  int j = 0;
  while (j < 11 && blk >= J.boff[j + 1]) ++j;
  int id = (blk - J.boff[j]) * 256 + threadIdx.x;  // < K*32 exactly
  int K = J.K[j];
  int l = id & 63;
  int c = (id >> 6) & 15;
  int ks = id >> 10;
  int n = c * 16 + (l & 15);
  int k = ks * 32 + (l >> 4) * 8;
  const float* src = J.src[j] + (size_t)n * K + k;
  uint4 o;
  o.x = pk2(src[0], src[1]);
  o.y = pk2(src[2], src[3]);
  o.z = pk2(src[4], src[5]);
  o.w = pk2(src[6], src[7]);
  *(uint4*)(J.dst[j] + (size_t)id * 8) = o;
}

// ---------------- bias combine (all 6, one launch) ----------------
struct BiasJobs {
  const float* a[6];
  const float* b[6];
  float* o[6];
};
__global__ void bias_all(BiasJobs J) {
  int j = blockIdx.x;
  int i = threadIdx.x;
  J.o[j][i] = J.a[j][i] + J.b[j][i];
}

// ---------------- FUSED gather(LDS) + SAGE GEMM, bf16 MFMA ----------------
// out[i,:] = elu( mean_{j in N(i)} feat[j,:] @ Wl^T + x[i,:] @ Wr^T + bias )
// Block: 512 thr = 8 waves; tile = 64 rows x 256 cols.
// Phase G: each wave gathers 8 dst rows ONCE (full 512B contiguous row reads,
//   same pattern as the standalone gather) -> mean in f32 regs -> bf16 into a
//   XOR-swizzled LDS agg tile (byte ^= (row&7)<<4; G4 fix for the stride-512B
//   row-major fragment reads). agg HBM round-trip (154 MB/layer) eliminated.
// Phase K: counted-vmcnt 3-buffer weight pipeline (R12/R14-verified). Wave =
//   16 rows (rw 0..3) x 128 cols (cw 0..1, 8 ctiles), acc[8]. Stage s issues
//   {wstage(s+2): 2 DMA, xload(s+2): 1 if phase-2} then MFMAs chunk s, then
//   s_waitcnt vmcnt(3/2) + s_barrier (this stage's ops stay in flight; ops for
//   s+1 landed 2 stages ago). LDS: 3x16 KB W + <=32 KB agg = 80 KB, 2 blk/CU.
struct SideF {
  const u16* feat;   // gather source features (K1 wide)
  const int* cs;     // CSR src indices grouped by dst
  const int* rs;     // CSR row_start per dst node
  const u16* x;      // dst features (K2 wide)
  const u16* Wp;     // packed [Wl|Wr], (K1+K2)*256 u16, chunk-major 16 KB
  const float* bias;
  u16* out;
  int M;
};

template <int K1C, int K2C>
__device__ __forceinline__ void sage_side(const SideF S, int bid, u16* ldsw, u16* agg) {
  constexpr int NK = K1C + K2C;
  const int t = threadIdx.x;
  const int w = t >> 6, l = t & 63;
  const int rw = w & 3, cw = w >> 2;
  const int lr = l & 15, lk = l >> 4;
  const int row0 = bid * 64;

  // weight DMA for chunk c into buffer b: 2 ops, 512 thr x 16 B x2 = 16 KB
  auto wstage = [&](int c, int b) {
    const u16* g = S.Wp + (size_t)c * 8192 + (size_t)t * 8;
    u16* d = ldsw + b * 8192 + w * 512;  // wave-uniform base; HW adds lane*16
    gload_lds16(g, d);
    gload_lds16(g + 4096, d + 4096);
  };

  // prologue DMAs: chunks 0,1 land during the gather phase
  wstage(0, 0);
  wstage(1, 1);

  // ---- phase G: wave w gathers local rows w*8 .. w*8+7 into LDS agg ----
  for (int rr = 0; rr < 8; ++rr) {
    const int lrow = w * 8 + rr;
    const int ar = min(row0 + lrow, S.M - 1);
    const int beg = S.rs[ar], end = S.rs[ar + 1];
    const float inv = 1.0f / fmaxf((float)(end - beg), 1.0f);
    if (K1C == 8) {  // K1=256: 4 bf16 (8 B) per lane per edge row
      float a0 = 0.f, a1 = 0.f, a2 = 0.f, a3 = 0.f;
      int e = beg;
      uint2 un = {0, 0};
      if (e < end) un = *(const uint2*)(S.feat + (size_t)S.cs[e] * 256 + l * 4);
      while (e < end) {
        uint2 u = un;
        ++e;
        if (e < end)  // issue next row load before consuming current
          un = *(const uint2*)(S.feat + (size_t)S.cs[e] * 256 + l * 4);
        a0 += lo_f(u.x); a1 += hi_f(u.x);
        a2 += lo_f(u.y); a3 += hi_f(u.y);
      }
      uint2 o;
      o.x = pk2(a0 * inv, a1 * inv);
      o.y = pk2(a2 * inv, a3 * inv);
      const u32 byte = (u32)(lrow * 512 + l * 8) ^ (u32)((lrow & 7) << 4);
      *(uint2*)((char*)agg + byte) = o;
    } else {  // K1C==4, K1=128: 2 bf16 (4 B) per lane per edge row
      float a0 = 0.f, a1 = 0.f;
      int e = beg;
      u32 un = 0;
      if (e < end) un = *(const u32*)(S.feat + (size_t)S.cs[e] * 128 + l * 2);
      while (e < end) {
        u32 u = un;
        ++e;
        if (e < end)
          un = *(const u32*)(S.feat + (size_t)S.cs[e] * 128 + l * 2);
        a0 += lo_f(u); a1 += hi_f(u);
      }
      const u32 byte = (u32)(lrow * 256 + l * 4) ^ (u32)((lrow & 7) << 4);
      *(u32*)((char*)agg + byte) = pk2(a0 * inv, a1 * inv);
    }
  }
  __syncthreads();  // agg visible to all; prologue DMAs drained

  // ---- phase K: GEMM over NK chunks ----
  const int grow = row0 + rw * 16 + lr;
  const int ar = min(grow, S.M - 1);
  const u16* px = S.x + (size_t)ar * (K2C * 32) + lk * 8;

  f32x4 acc[8];
  #pragma unroll
  for (int i = 0; i < 8; ++i) acc[i] = (f32x4){0.f, 0.f, 0.f, 0.f};

  v8s xc = {}, xn = {}, xn2 = {};
  const int lrow = rw * 16 + lr;
  const u32 aswz = (u32)((lrow & 7) << 4);

  #pragma unroll
  for (int s = 0; s < NK; ++s) {
    const int cur = s % 3;
    if (s + 2 < NK) wstage(s + 2, (s + 2) % 3);            // 2 VMEM ops
    if (s + 2 >= K1C && s + 2 < NK)                        // 1 VMEM op
      xn2 = *(const v8s*)(px + (s + 2 - K1C) * 32);

    v8s af;
    if (s < K1C) {  // A from LDS agg (swizzled ds_read_b128)
      const u32 byte = (u32)(lrow * (K1C * 64) + s * 64 + lk * 16) ^ aswz;
      af = *(const v8s*)((char*)agg + byte);
    } else {
      af = xc;
    }
    const u16* lw = ldsw + cur * 8192 + cw * 4096 + (size_t)l * 8;
    #pragma unroll
    for (int i = 0; i < 8; ++i) {
      v8s wf = *(const v8s*)(lw + i * 512);
      acc[i] = __builtin_amdgcn_mfma_f32_16x16x32_bf16(wf, af, acc[i], 0, 0, 0);
    }
    if (s + 1 < NK) {
      if (s + 2 < NK) {
        if (s + 2 >= K1C) {
          asm volatile("s_waitcnt vmcnt(3)" ::: "memory");  // 3 ops this stage
        } else {
          asm volatile("s_waitcnt vmcnt(2)" ::: "memory");  // 2 ops this stage
        }
      } else {
        asm volatile("s_waitcnt vmcnt(0)" ::: "memory");    // tail drain
      }
      __builtin_amdgcn_s_barrier();
      xc = xn;
      xn = xn2;
    }
  }

  // epilogue: bias + ELU + bf16 store
  const int colb = cw * 128 + lk * 4;
  if (grow < S.M) {
    u16* orow = S.out + (size_t)grow * 256 + colb;
    #pragma unroll
    for (int i = 0; i < 8; ++i) {
      f32x4 bv = *(const f32x4*)(S.bias + colb + i * 16);
      float e0 = elu_f(acc[i][0] + bv[0]);
      float e1 = elu_f(acc[i][1] + bv[1]);
      float e2 = elu_f(acc[i][2] + bv[2]);
      float e3 = elu_f(acc[i][3] + bv[3]);
      uint2 o;
      o.x = pk2(e0, e1);
      o.y = pk2(e2, e3);
      *(uint2*)(orow + i * 16) = o;
    }
  }
}

template <int K1P, int K2P, int K1A, int K2A>
__global__ __launch_bounds__(512, 4) void sage_fuse(SideF P, SideF A, int nbP) {
  __shared__ __align__(16) u16 lds_mem[40960];  // 48 KB weights + 32 KB agg
  int bid = blockIdx.x;
  if (bid < nbP) sage_side<K1P, K2P>(P, bid, lds_mem, lds_mem + 24576);
  else           sage_side<K1A, K2A>(A, bid - nbP, lds_mem, lds_mem + 24576);
}

// ---------------- output projection (bf16 author) ----------------
__global__ __launch_bounds__(256) void out_proj(const u16* __restrict__ author,
                                                const float* __restrict__ W,
                                                const float* __restrict__ b,
                                                float* __restrict__ out, int M) {
  __shared__ float ws[10 * 256];
  __shared__ float bs[10];
  int t = threadIdx.x;
  for (int i = t; i < 2560; i += 256) ws[i] = W[i];
  if (t < 10) bs[t] = b[t];
  __syncthreads();
  int wave = t >> 6, lane = t & 63;
  int row = blockIdx.x * 4 + wave;
  if (row >= M) return;
  ushort4 u = *(const ushort4*)(author + (size_t)row * 256 + lane * 4);
  float a0 = bf2f(u.x), a1 = bf2f(u.y), a2 = bf2f(u.z), a3 = bf2f(u.w);
  float p[10];
  #pragma unroll
  for (int n = 0; n < 10; ++n) {
    const float* wv = ws + n * 256 + lane * 4;
    p[n] = a0 * wv[0] + a1 * wv[1] + a2 * wv[2] + a3 * wv[3];
  }
  #pragma unroll
  for (int off = 32; off > 0; off >>= 1) {
    #pragma unroll
    for (int n = 0; n < 10; ++n) p[n] += __shfl_down(p[n], off);
  }
  if (lane == 0) {
    #pragma unroll
    for (int n = 0; n < 10; ++n) out[(size_t)row * 10 + n] = p[n] + bs[n];
  }
}

extern "C" void kernel_launch(void* const* d_in, const int* in_sizes, int n_in,
                              void* d_out, int out_size, void* d_ws, size_t ws_size,
                              hipStream_t stream) {
  const float* x_author = (const float*)d_in[0];
  const float* x_paper  = (const float*)d_in[1];
  const int* ei_a2p = (const int*)d_in[2];
  const int* ei_p2a = (const int*)d_in[3];
  const int* src_ap = ei_a2p;       // author indices
  const int* dst_ap = ei_a2p + NE;  // paper indices
  const int* src_pa = ei_p2a;       // paper indices
  const int* dst_pa = ei_p2a + NE;  // author indices
  const float* Wl0_ap = (const float*)d_in[4];
  const float* bl0_ap = (const float*)d_in[5];
  const float* Wr0_ap = (const float*)d_in[6];
  const float* br0_ap = (const float*)d_in[7];
  const float* Wl0_pa = (const float*)d_in[8];
  const float* bl0_pa = (const float*)d_in[9];
  const float* Wr0_pa = (const float*)d_in[10];
  const float* br0_pa = (const float*)d_in[11];
  const float* Wl_ap = (const float*)d_in[12];
  const float* bl_ap = (const float*)d_in[13];
  const float* Wr_ap = (const float*)d_in[14];
  const float* br_ap = (const float*)d_in[15];
  const float* Wl_pa = (const float*)d_in[16];
  const float* bl_pa = (const float*)d_in[17];
  const float* Wr_pa = (const float*)d_in[18];
  const float* br_pa = (const float*)d_in[19];
  const float* W_out = (const float*)d_in[20];
  const float* b_out = (const float*)d_in[21];
  float* out = (float*)d_out;

  // ---- workspace layout (byte offsets, 256B-aligned chunks) ----
  char* base = (char*)d_ws;
  size_t o = 0;
  auto alloc = [&](size_t bytes) {
    void* p = base + o;
    o += (bytes + 255) & ~(size_t)255;
    return p;
  };
  u16* paper   = (u16*)alloc((size_t)NP * 256 * 2);
  u16* author  = (u16*)alloc((size_t)NA * 256 * 2);
  u16* paper2  = (u16*)alloc((size_t)NP * 256 * 2);
  u16* author2 = (u16*)alloc((size_t)NA * 256 * 2);
  u16* xp_bf  = (u16*)alloc((size_t)NP * 256 * 2);
  u16* xa_bf  = (u16*)alloc((size_t)NA * 128 * 2);
  u16* wc0_p = (u16*)alloc((128 + 256) * 256 * 2);        // [Wl0_ap | Wr0_ap]
  u16* wc0_a = (u16*)alloc((256 + 128) * 256 * 2);        // [Wl0_pa | Wr0_pa]
  u16* wc_ap = (u16*)alloc((size_t)2 * 512 * 256 * 2);    // per layer: [Wl | Wr]
  u16* wc_pa = (u16*)alloc((size_t)2 * 512 * 256 * 2);
  float* bias0_ap = (float*)alloc(256 * 4);
  float* bias0_pa = (float*)alloc(256 * 4);
  float* bias_ap  = (float*)alloc(2 * 256 * 4);
  float* bias_pa  = (float*)alloc(2 * 256 * 4);
  int* cnt_p  = (int*)alloc((size_t)(NP + NA) * 4);  // cnt_p + cnt_a contiguous
  int* cnt_a  = cnt_p + NP;
  int* rs_p   = (int*)alloc((size_t)(NP + 1) * 4);
  int* rs_a   = (int*)alloc((size_t)(NA + 1) * 4);
  int* cur_p  = (int*)alloc((size_t)NP * 4);
  int* cur_a  = (int*)alloc((size_t)NA * 4);
  int* csrc_p = (int*)alloc((size_t)NE * 4);
  int* csrc_a = (int*)alloc((size_t)NE * 4);
  int* bsum_p = (int*)alloc(128 * 4);
  int* bsum_a = (int*)alloc(128 * 4);

  const int NBP = (NP + SCAN_CHUNK - 1) / SCAN_CHUNK;  // 98
  const int NBA = (NA + SCAN_CHUNK - 1) / SCAN_CHUNK;  // 49

  // ---- CSR build (once, reused by all 3 layers) ----
  hipMemsetAsync(cnt_p, 0, (size_t)(NP + NA) * 4, stream);
  count_deg_i<<<(2 * NE + 255) / 256, 256, 0, stream>>>(dst_ap, dst_pa, cnt_p, cnt_a);
  block_sums_k<<<NBP, 256, 0, stream>>>(cnt_p, bsum_p, NP);
  block_sums_k<<<NBA, 256, 0, stream>>>(cnt_a, bsum_a, NA);
  scan_bsums_k<<<1, 256, 0, stream>>>(bsum_p, NBP);
  scan_bsums_k<<<1, 256, 0, stream>>>(bsum_a, NBA);
  scan_final_k<<<NBP, 256, 0, stream>>>(cnt_p, bsum_p, rs_p, cur_p, NP, NE);
  scan_final_k<<<NBA, 256, 0, stream>>>(cnt_a, bsum_a, rs_a, cur_a, NA, NE);
  csr_fill<<<(NE + 255) / 256, 256, 0, stream>>>(src_ap, dst_ap, cur_p, csrc_p);
  csr_fill<<<(NE + 255) / 256, 256, 0, stream>>>(src_pa, dst_pa, cur_a, csrc_a);

  // ---- input conversion to bf16 ----
  to_bf16<<<((NP * 256 / 4) + 255) / 256, 256, 0, stream>>>(x_paper, xp_bf, NP * 256 / 4);
  to_bf16<<<((NA * 128 / 4) + 255) / 256, 256, 0, stream>>>(x_author, xa_bf, NA * 128 / 4);

  // ---- weight pack (single launch) ----
  {
    PackJobs J;
    const float* srcs[12] = {Wl0_ap, Wr0_ap, Wl0_pa, Wr0_pa,
                             Wl_ap, Wr_ap, Wl_pa, Wr_pa,
                             Wl_ap + 65536, Wr_ap + 65536, Wl_pa + 65536, Wr_pa + 65536};
    u16* dsts[12] = {wc0_p, wc0_p + 128 * 256, wc0_a, wc0_a + 256 * 256,
                     wc_ap, wc_ap + 65536, wc_pa, wc_pa + 65536,
                     wc_ap + 131072, wc_ap + 131072 + 65536,
                     wc_pa + 131072, wc_pa + 131072 + 65536};
    int Ks[12] = {128, 256, 256, 128, 256, 256, 256, 256, 256, 256, 256, 256};
    int off = 0;
    for (int j = 0; j < 12; ++j) {
      J.src[j] = srcs[j];
      J.dst[j] = dsts[j];
      J.K[j] = Ks[j];
      J.boff[j] = off;
      off += Ks[j] / 8;
    }
    J.boff[12] = off;
    pack_all<<<off, 256, 0, stream>>>(J);
  }
  // ---- bias combine (single launch) ----
  {
    BiasJobs J;
    const float* as[6] = {bl0_ap, bl0_pa, bl_ap, bl_ap + 256, bl_pa, bl_pa + 256};
    const float* bs[6] = {br0_ap, br0_pa, br_ap, br_ap + 256, br_pa, br_pa + 256};
    float* os[6] = {bias0_ap, bias0_pa, bias_ap, bias_ap + 256, bias_pa, bias_pa + 256};
    for (int j = 0; j < 6; ++j) { J.a[j] = as[j]; J.b[j] = bs[j]; J.o[j] = os[j]; }
    bias_all<<<6, 256, 0, stream>>>(J);
  }

  // fused-layer grids: 64 rows x 256 cols per 512-thread block
  const int nbP = (NP + 63) / 64;   // 1563
  const int nbA = (NA + 63) / 64;   // 782

  // ---- layer 0: (x_author 128, x_paper 256) -> paper, author ----
  sage_fuse<4, 8, 8, 4><<<nbP + nbA, 512, 0, stream>>>(
      SideF{xa_bf, csrc_p, rs_p, xp_bf, wc0_p, bias0_ap, paper, NP},
      SideF{xp_bf, csrc_a, rs_a, xa_bf, wc0_a, bias0_pa, author, NA}, nbP);

  // ---- layer 1: (paper, author) -> (paper2, author2) ----
  sage_fuse<8, 8, 8, 8><<<nbP + nbA, 512, 0, stream>>>(
      SideF{author, csrc_p, rs_p, paper, wc_ap, bias_ap, paper2, NP},
      SideF{paper, csrc_a, rs_a, author, wc_pa, bias_pa, author2, NA}, nbP);

  // ---- layer 2: AUTHOR SIDE ONLY (final paper is dead code — the reference
  //      returns author @ W_out; paper from the last layer is never consumed) ----
  sage_fuse<8, 8, 8, 8><<<nbA, 512, 0, stream>>>(
      SideF{paper2, csrc_a, rs_a, author2, wc_pa + 131072, bias_pa + 256, author, NA},
      SideF{paper2, csrc_a, rs_a, author2, wc_pa + 131072, bias_pa + 256, author, NA}, 0);

  // ---- output projection ----
  out_proj<<<(NA + 3) / 4, 256, 0, stream>>>(author, W_out, b_out, out, NA);
}

// Round 17
// 441.588 us; speedup vs baseline: 1.2548x; 1.2548x over previous
//
#include <hip/hip_runtime.h>
#include <hip/hip_bf16.h>
#include <cstddef>

#define NA 50000
#define NP 100000
#define NE 200000
#define SCAN_CHUNK 1024

typedef unsigned short u16;
typedef unsigned int u32;
typedef short v8s __attribute__((ext_vector_type(8)));
typedef float f32x4 __attribute__((ext_vector_type(4)));

__device__ __forceinline__ float elu_f(float x) {
  return x > 0.0f ? x : expm1f(x);
}
__device__ __forceinline__ u16 f2bf(float x) {
  u32 u = __float_as_uint(x);
  return (u16)((u + 0x7fffu + ((u >> 16) & 1u)) >> 16);
}
__device__ __forceinline__ float bf2f(u16 h) {
  return __uint_as_float(((u32)h) << 16);
}
__device__ __forceinline__ u32 pk2(float a, float b) {
  return (u32)f2bf(a) | ((u32)f2bf(b) << 16);
}
__device__ __forceinline__ float lo_f(u32 w) { return __uint_as_float(w << 16); }
__device__ __forceinline__ float hi_f(u32 w) { return __uint_as_float(w & 0xffff0000u); }

// async global->LDS, 16B per lane; ldst must be wave-uniform (HW adds lane*16)
__device__ __forceinline__ void gload_lds16(const u16* gsrc, u16* ldst) {
  __builtin_amdgcn_global_load_lds(
      (const __attribute__((address_space(1))) u32*)gsrc,
      (__attribute__((address_space(3))) u32*)ldst, 16, 0, 0);
}

// ---------------- degree counting (int) ----------------
__global__ void count_deg_i(const int* __restrict__ dst_p, const int* __restrict__ dst_a,
                            int* cnt_p, int* cnt_a) {
  int i = blockIdx.x * blockDim.x + threadIdx.x;
  if (i < NE) atomicAdd(&cnt_p[dst_p[i]], 1);
  else if (i < 2 * NE) atomicAdd(&cnt_a[dst_a[i - NE]], 1);
}

// ---------------- 3-kernel exclusive scan (p and a fused per launch) ----------------
__global__ void block_sums2(const int* __restrict__ cnt_p, int* __restrict__ bsum_p, int nbp,
                            const int* __restrict__ cnt_a, int* __restrict__ bsum_a) {
  __shared__ int red[256];
  int b = blockIdx.x;
  const int* cnt;
  int* bsums;
  int n;
  if (b < nbp) { cnt = cnt_p; bsums = bsum_p; n = NP; }
  else         { b -= nbp; cnt = cnt_a; bsums = bsum_a; n = NA; }
  int t = threadIdx.x;
  int base = b * SCAN_CHUNK + t * 4;
  int s = 0;
  #pragma unroll
  for (int i = 0; i < 4; ++i) {
    int idx = base + i;
    if (idx < n) s += cnt[idx];
  }
  red[t] = s;
  __syncthreads();
  for (int off = 128; off > 0; off >>= 1) {
    if (t < off) red[t] += red[t + off];
    __syncthreads();
  }
  if (t == 0) bsums[b] = red[0];
}

__global__ void scan_bsums2(int* bsum_p, int nbp, int* bsum_a, int nba) {
  __shared__ int tmp[256];
  int* bsums = blockIdx.x ? bsum_a : bsum_p;
  int nb = blockIdx.x ? nba : nbp;
  int t = threadIdx.x;
  int orig = (t < nb) ? bsums[t] : 0;
  tmp[t] = orig;
  __syncthreads();
  for (int off = 1; off < 256; off <<= 1) {
    int u = (t >= off) ? tmp[t - off] : 0;
    __syncthreads();
    tmp[t] += u;
    __syncthreads();
  }
  if (t < nb) bsums[t] = tmp[t] - orig;  // exclusive
}

// writes row_start AND cursor copy, both sides in one launch
__global__ void scan_final2(const int* __restrict__ cnt_p, const int* __restrict__ bsum_p,
                            int* __restrict__ rs_p, int* __restrict__ cur_p, int nbp,
                            const int* __restrict__ cnt_a, const int* __restrict__ bsum_a,
                            int* __restrict__ rs_a, int* __restrict__ cur_a) {
  __shared__ int red[256];
  int b = blockIdx.x;
  const int *cnt, *bsums;
  int *row_start, *cursor;
  int n;
  if (b < nbp) { cnt = cnt_p; bsums = bsum_p; row_start = rs_p; cursor = cur_p; n = NP; }
  else { b -= nbp; cnt = cnt_a; bsums = bsum_a; row_start = rs_a; cursor = cur_a; n = NA; }
  int t = threadIdx.x;
  int base = b * SCAN_CHUNK + t * 4;
  int v[4];
  int s = 0;
  #pragma unroll
  for (int i = 0; i < 4; ++i) {
    int idx = base + i;
    v[i] = (idx < n) ? cnt[idx] : 0;
    s += v[i];
  }
  int orig = s;
  red[t] = s;
  __syncthreads();
  for (int off = 1; off < 256; off <<= 1) {
    int u = (t >= off) ? red[t - off] : 0;
    __syncthreads();
    red[t] += u;
    __syncthreads();
  }
  int excl = red[t] - orig + bsums[b];
  #pragma unroll
  for (int i = 0; i < 4; ++i) {
    int idx = base + i;
    if (idx < n) {
      row_start[idx] = excl;
      cursor[idx] = excl;
    }
    excl += v[i];
  }
  if (b == 0 && t == 0) row_start[n] = NE;
}

__global__ void csr_fill2(const int* __restrict__ src_p, const int* __restrict__ dst_p,
                          int* cur_p, int* __restrict__ csrc_p,
                          const int* __restrict__ src_a, const int* __restrict__ dst_a,
                          int* cur_a, int* __restrict__ csrc_a) {
  int e = blockIdx.x * blockDim.x + threadIdx.x;
  if (e < NE) {
    int p = atomicAdd(&cur_p[dst_p[e]], 1);
    csrc_p[p] = src_p[e];
  } else if (e < 2 * NE) {
    int i = e - NE;
    int p = atomicAdd(&cur_a[dst_a[i]], 1);
    csrc_a[p] = src_a[i];
  }
}

// ---------------- f32 -> bf16 bulk convert (both inputs, one launch) ----------------
__global__ void to_bf16_2(const float* __restrict__ inp, u16* __restrict__ outp, int n4p,
                          const float* __restrict__ ina, u16* __restrict__ outa, int n4a) {
  int i = blockIdx.x * 256 + threadIdx.x;
  const float* in;
  u16* out;
  if (i < n4p) { in = inp; out = outp; }
  else {
    i -= n4p;
    if (i >= n4a) return;
    in = ina; out = outa;
  }
  float4 v = ((const float4*)in)[i];
  uint2 o;
  o.x = pk2(v.x, v.y);
  o.y = pk2(v.z, v.w);
  *(uint2*)(out + (size_t)i * 4) = o;
}

// ---------------- weight pack (all matrices, one launch) ----------------
// W: [256][K] f32 -> Wp[ks][c 16][lane 64][8] bf16
struct PackJobs {
  const float* src[12];
  u16* dst[12];
  int K[12];
  int boff[13];
};

__global__ void pack_all(PackJobs J) {
  int blk = blockIdx.x;
  int j = 0;
  while (j < 11 && blk >= J.boff[j + 1]) ++j;
  int id = (blk - J.boff[j]) * 256 + threadIdx.x;  // < K*32 exactly
  int K = J.K[j];
  int l = id & 63;
  int c = (id >> 6) & 15;
  int ks = id >> 10;
  int n = c * 16 + (l & 15);
  int k = ks * 32 + (l >> 4) * 8;
  const float* src = J.src[j] + (size_t)n * K + k;
  uint4 o;
  o.x = pk2(src[0], src[1]);
  o.y = pk2(src[2], src[3]);
  o.z = pk2(src[4], src[5]);
  o.w = pk2(src[6], src[7]);
  *(uint4*)(J.dst[j] + (size_t)id * 8) = o;
}

// ---------------- bias combine (all 6, one launch) ----------------
struct BiasJobs {
  const float* a[6];
  const float* b[6];
  float* o[6];
};
__global__ void bias_all(BiasJobs J) {
  int j = blockIdx.x;
  int i = threadIdx.x;
  J.o[j][i] = J.a[j][i] + J.b[j][i];
}

// ---------------- gather-mean, half-wave (32 lanes) per node, 2-deep pipeline ----------------
template <int D>
__device__ __forceinline__ void gm_node(const u16* __restrict__ feat, const int* __restrict__ cs,
                                        const int* __restrict__ rs, u16* __restrict__ agg,
                                        int node, int lane) {
  int beg = rs[node], end = rs[node + 1];
  int deg = end - beg;
  if (D == 256) {  // 8 elems/lane, 16B loads
    float a0 = 0.f, a1 = 0.f, a2 = 0.f, a3 = 0.f, a4 = 0.f, a5 = 0.f, a6 = 0.f, a7 = 0.f;
    int e = beg;
    uint4 un = {0, 0, 0, 0};
    if (e < end) un = *(const uint4*)(feat + (size_t)cs[e] * 256 + lane * 8);
    while (e < end) {
      uint4 u = un;
      ++e;
      if (e < end)  // issue next row load before consuming current
        un = *(const uint4*)(feat + (size_t)cs[e] * 256 + lane * 8);
      a0 += lo_f(u.x); a1 += hi_f(u.x);
      a2 += lo_f(u.y); a3 += hi_f(u.y);
      a4 += lo_f(u.z); a5 += hi_f(u.z);
      a6 += lo_f(u.w); a7 += hi_f(u.w);
    }
    float inv = 1.0f / fmaxf((float)deg, 1.0f);
    uint4 o;
    o.x = pk2(a0 * inv, a1 * inv);
    o.y = pk2(a2 * inv, a3 * inv);
    o.z = pk2(a4 * inv, a5 * inv);
    o.w = pk2(a6 * inv, a7 * inv);
    *(uint4*)(agg + (size_t)node * 256 + lane * 8) = o;
  } else {  // D=128: 4 elems/lane, 8B loads
    float a0 = 0.f, a1 = 0.f, a2 = 0.f, a3 = 0.f;
    int e = beg;
    uint2 un = {0, 0};
    if (e < end) un = *(const uint2*)(feat + (size_t)cs[e] * 128 + lane * 4);
    while (e < end) {
      uint2 u = un;
      ++e;
      if (e < end)
        un = *(const uint2*)(feat + (size_t)cs[e] * 128 + lane * 4);
      a0 += lo_f(u.x); a1 += hi_f(u.x);
      a2 += lo_f(u.y); a3 += hi_f(u.y);
    }
    float inv = 1.0f / fmaxf((float)deg, 1.0f);
    uint2 o;
    o.x = pk2(a0 * inv, a1 * inv);
    o.y = pk2(a2 * inv, a3 * inv);
    *(uint2*)(agg + (size_t)node * 128 + lane * 4) = o;
  }
}

// fused gather for both node types in one dispatch (half-wave per node)
template <int D1, int D2>
__global__ __launch_bounds__(256) void gather2(
    const u16* __restrict__ f1, const int* __restrict__ cs1, const int* __restrict__ rs1,
    u16* __restrict__ a1, int n1,
    const u16* __restrict__ f2, const int* __restrict__ cs2, const int* __restrict__ rs2,
    u16* __restrict__ a2, int n2) {
  int hw = (blockIdx.x * 256 + threadIdx.x) >> 5;
  int lane = threadIdx.x & 31;
  if (hw < n1) gm_node<D1>(f1, cs1, rs1, a1, hw, lane);
  else if (hw - n1 < n2) gm_node<D2>(f2, cs2, rs2, a2, hw - n1, lane);
}

// ---------------- SAGE update: counted-vmcnt 3-buffer pipeline + XCD-chunked swizzle ----------------
// out[i,:] = elu( agg[i,:] @ Wl^T + x[i,:] @ Wr^T + bias ), Wp packed [Wl|Wr].
// Block: 512 thr = 8 waves; tile = 256 rows x 128 cols (cg = bid&1). Wave: 32 rows
// (2 x 16-row MFMA tiles) x 128 cols (8 ctiles), acc[2][8]. K-chunks of 32 (8 KB
// weight slices, 3 LDS buffers). Stage s issues exactly {wstage(s+2), xload(s+2)x2}
// = 3 VMEM ops, MFMAs chunk s, then `s_waitcnt vmcnt(3)` + s_barrier: this stage's
// ops stay in flight, ops for s+1 landed 2 stages ago. Prologue drains once.
// XCD swizzle (T1, m204 bijective): HW round-robins orig%8 across XCDs; the
// chunked remap gives each XCD a contiguous logical-bid range, so the cg-sibling
// pair (2rg, 2rg+1) and consecutive row-groups share one XCD -> the x2 activation
// re-read hits the 4MB per-XCD L2 instead of L3. Write geometry unchanged.
struct SideB {
  const u16* agg;
  const u16* x;
  const u16* Wp;     // packed, (K1+K2)*256 u16, chunk-major
  const float* bias;
  u16* out;
  int M;
  int K1;
  int K2;
};

template <int NK>
__global__ __launch_bounds__(512, 4) void sage_pipe(SideB P, SideB A, int nbP2, int nwg) {
  __shared__ __align__(16) u16 ldsw[3 * 4096];  // 3 x 8 KB
  // bijective XCD-chunked remap (m204): orig%8 = XCD; logical bids chunked per XCD
  int bid;
  {
    const int orig = blockIdx.x;
    const int q = nwg >> 3, r = nwg & 7;
    const int xcd = orig & 7, slot = orig >> 3;
    bid = (xcd < r ? xcd * (q + 1) : r * (q + 1) + (xcd - r) * q) + slot;
  }
  SideB S;
  if (bid < nbP2) { S = P; } else { bid -= nbP2; S = A; }
  const int cg = bid & 1;
  const int rg = bid >> 1;

  const int k1c = S.K1 >> 5;
  const int t = threadIdx.x;
  const int w = t >> 6, l = t & 63;
  const int lr = l & 15, lk = l >> 4;
  const int rowbase = rg * 256 + w * 32;

  int rowv[2];
  const u16 *pa[2], *px[2];
  #pragma unroll
  for (int rt = 0; rt < 2; ++rt) {
    int row = rowbase + rt * 16 + lr;
    rowv[rt] = row;
    int ar = min(row, S.M - 1);
    pa[rt] = S.agg + (size_t)ar * S.K1 + lk * 8;
    px[rt] = S.x + (size_t)ar * S.K2 + lk * 8;
  }

  auto xload = [&](int c, int rt) -> v8s {
    const u16* p = (c < k1c) ? (pa[rt] + c * 32) : (px[rt] + (c - k1c) * 32);
    return *(const v8s*)p;
  };
  // weight DMA for chunk c into LDS buffer b: per-lane global src, wave-uniform dest
  auto wstage = [&](int c, int b) {
    const u16* gsrc = S.Wp + ((size_t)c * 1024 + cg * 512 + t) * 8;
    u16* ldst = ldsw + b * 4096 + w * 512;  // wave-uniform (w uniform per wave)
    gload_lds16(gsrc, ldst);
  };

  f32x4 acc[2][8];
  #pragma unroll
  for (int rt = 0; rt < 2; ++rt)
    #pragma unroll
    for (int i = 0; i < 8; ++i) acc[rt][i] = (f32x4){0.f, 0.f, 0.f, 0.f};

  // prologue: buffers 0,1 + x for chunks 0,1; one-time full drain
  v8s xc[2], xn[2], xn2[2];
  wstage(0, 0);
  wstage(1, 1);
  xc[0] = xload(0, 0);
  xc[1] = xload(0, 1);
  if (NK > 1) {
    xn[0] = xload(1, 0);
    xn[1] = xload(1, 1);
  }
  asm volatile("s_waitcnt vmcnt(0)" ::: "memory");
  __builtin_amdgcn_s_barrier();

  #pragma unroll
  for (int s = 0; s < NK; ++s) {
    const int cur = s % 3;
    if (s + 2 < NK) {  // exactly 3 VMEM ops this stage, all for stage s+2
      wstage(s + 2, (s + 2) % 3);
      xn2[0] = xload(s + 2, 0);
      xn2[1] = xload(s + 2, 1);
    }
    const u16* lw = ldsw + cur * 4096 + (size_t)l * 8;
    #pragma unroll
    for (int i = 0; i < 8; ++i) {
      v8s wf = *(const v8s*)(lw + i * 512);
      acc[0][i] = __builtin_amdgcn_mfma_f32_16x16x32_bf16(wf, xc[0], acc[0][i], 0, 0, 0);
      acc[1][i] = __builtin_amdgcn_mfma_f32_16x16x32_bf16(wf, xc[1], acc[1][i], 0, 0, 0);
    }
    if (s + 1 < NK) {
      if (s + 2 < NK) {
        asm volatile("s_waitcnt vmcnt(3)" ::: "memory");  // keep this stage's 3 in flight
      } else {
        asm volatile("s_waitcnt vmcnt(0)" ::: "memory");  // tail: nothing new issued
      }
      __builtin_amdgcn_s_barrier();
      xc[0] = xn[0];  xc[1] = xn[1];
      xn[0] = xn2[0]; xn[1] = xn2[1];
    }
  }

  // epilogue: bias + ELU + bf16 store (256 B contiguous per row per block half)
  const int colb = cg * 128 + lk * 4;
  #pragma unroll
  for (int rt = 0; rt < 2; ++rt) {
    if (rowv[rt] < S.M) {
      u16* orow = S.out + (size_t)rowv[rt] * 256 + colb;
      #pragma unroll
      for (int i = 0; i < 8; ++i) {
        f32x4 bv = *(const f32x4*)(S.bias + colb + i * 16);
        float e0 = elu_f(acc[rt][i][0] + bv[0]);
        float e1 = elu_f(acc[rt][i][1] + bv[1]);
        float e2 = elu_f(acc[rt][i][2] + bv[2]);
        float e3 = elu_f(acc[rt][i][3] + bv[3]);
        uint2 o;
        o.x = pk2(e0, e1);
        o.y = pk2(e2, e3);
        *(uint2*)(orow + i * 16) = o;
      }
    }
  }
}

// ---------------- output projection (bf16 author) ----------------
__global__ __launch_bounds__(256) void out_proj(const u16* __restrict__ author,
                                                const float* __restrict__ W,
                                                const float* __restrict__ b,
                                                float* __restrict__ out, int M) {
  __shared__ float ws[10 * 256];
  __shared__ float bs[10];
  int t = threadIdx.x;
  for (int i = t; i < 2560; i += 256) ws[i] = W[i];
  if (t < 10) bs[t] = b[t];
  __syncthreads();
  int wave = t >> 6, lane = t & 63;
  int row = blockIdx.x * 4 + wave;
  if (row >= M) return;
  ushort4 u = *(const ushort4*)(author + (size_t)row * 256 + lane * 4);
  float a0 = bf2f(u.x), a1 = bf2f(u.y), a2 = bf2f(u.z), a3 = bf2f(u.w);
  float p[10];
  #pragma unroll
  for (int n = 0; n < 10; ++n) {
    const float* wv = ws + n * 256 + lane * 4;
    p[n] = a0 * wv[0] + a1 * wv[1] + a2 * wv[2] + a3 * wv[3];
  }
  #pragma unroll
  for (int off = 32; off > 0; off >>= 1) {
    #pragma unroll
    for (int n = 0; n < 10; ++n) p[n] += __shfl_down(p[n], off);
  }
  if (lane == 0) {
    #pragma unroll
    for (int n = 0; n < 10; ++n) out[(size_t)row * 10 + n] = p[n] + bs[n];
  }
}

extern "C" void kernel_launch(void* const* d_in, const int* in_sizes, int n_in,
                              void* d_out, int out_size, void* d_ws, size_t ws_size,
                              hipStream_t stream) {
  const float* x_author = (const float*)d_in[0];
  const float* x_paper  = (const float*)d_in[1];
  const int* ei_a2p = (const int*)d_in[2];
  const int* ei_p2a = (const int*)d_in[3];
  const int* src_ap = ei_a2p;       // author indices
  const int* dst_ap = ei_a2p + NE;  // paper indices
  const int* src_pa = ei_p2a;       // paper indices
  const int* dst_pa = ei_p2a + NE;  // author indices
  const float* Wl0_ap = (const float*)d_in[4];
  const float* bl0_ap = (const float*)d_in[5];
  const float* Wr0_ap = (const float*)d_in[6];
  const float* br0_ap = (const float*)d_in[7];
  const float* Wl0_pa = (const float*)d_in[8];
  const float* bl0_pa = (const float*)d_in[9];
  const float* Wr0_pa = (const float*)d_in[10];
  const float* br0_pa = (const float*)d_in[11];
  const float* Wl_ap = (const float*)d_in[12];
  const float* bl_ap = (const float*)d_in[13];
  const float* Wr_ap = (const float*)d_in[14];
  const float* br_ap = (const float*)d_in[15];
  const float* Wl_pa = (const float*)d_in[16];
  const float* bl_pa = (const float*)d_in[17];
  const float* Wr_pa = (const float*)d_in[18];
  const float* br_pa = (const float*)d_in[19];
  const float* W_out = (const float*)d_in[20];
  const float* b_out = (const float*)d_in[21];
  float* out = (float*)d_out;

  // ---- workspace layout (byte offsets, 256B-aligned chunks) ----
  char* base = (char*)d_ws;
  size_t o = 0;
  auto alloc = [&](size_t bytes) {
    void* p = base + o;
    o += (bytes + 255) & ~(size_t)255;
    return p;
  };
  u16* paper   = (u16*)alloc((size_t)NP * 256 * 2);
  u16* author  = (u16*)alloc((size_t)NA * 256 * 2);
  u16* paper2  = (u16*)alloc((size_t)NP * 256 * 2);
  u16* author2 = (u16*)alloc((size_t)NA * 256 * 2);
  u16* agg_p  = (u16*)alloc((size_t)NP * 256 * 2);
  u16* agg_a  = (u16*)alloc((size_t)NA * 256 * 2);
  u16* xp_bf  = (u16*)alloc((size_t)NP * 256 * 2);
  u16* xa_bf  = (u16*)alloc((size_t)NA * 128 * 2);
  u16* wc0_p = (u16*)alloc((128 + 256) * 256 * 2);        // [Wl0_ap | Wr0_ap]
  u16* wc0_a = (u16*)alloc((256 + 128) * 256 * 2);        // [Wl0_pa | Wr0_pa]
  u16* wc_ap = (u16*)alloc((size_t)2 * 512 * 256 * 2);    // per layer: [Wl | Wr]
  u16* wc_pa = (u16*)alloc((size_t)2 * 512 * 256 * 2);
  float* bias0_ap = (float*)alloc(256 * 4);
  float* bias0_pa = (float*)alloc(256 * 4);
  float* bias_ap  = (float*)alloc(2 * 256 * 4);
  float* bias_pa  = (float*)alloc(2 * 256 * 4);
  int* cnt_p  = (int*)alloc((size_t)(NP + NA) * 4);  // cnt_p + cnt_a contiguous
  int* cnt_a  = cnt_p + NP;
  int* rs_p   = (int*)alloc((size_t)(NP + 1) * 4);
  int* rs_a   = (int*)alloc((size_t)(NA + 1) * 4);
  int* cur_p  = (int*)alloc((size_t)NP * 4);
  int* cur_a  = (int*)alloc((size_t)NA * 4);
  int* csrc_p = (int*)alloc((size_t)NE * 4);
  int* csrc_a = (int*)alloc((size_t)NE * 4);
  int* bsum_p = (int*)alloc(128 * 4);
  int* bsum_a = (int*)alloc(128 * 4);

  const int NBP = (NP + SCAN_CHUNK - 1) / SCAN_CHUNK;  // 98
  const int NBA = (NA + SCAN_CHUNK - 1) / SCAN_CHUNK;  // 49

  // ---- CSR build (once, reused by all 3 layers) ----
  hipMemsetAsync(cnt_p, 0, (size_t)(NP + NA) * 4, stream);
  count_deg_i<<<(2 * NE + 255) / 256, 256, 0, stream>>>(dst_ap, dst_pa, cnt_p, cnt_a);
  block_sums2<<<NBP + NBA, 256, 0, stream>>>(cnt_p, bsum_p, NBP, cnt_a, bsum_a);
  scan_bsums2<<<2, 256, 0, stream>>>(bsum_p, NBP, bsum_a, NBA);
  scan_final2<<<NBP + NBA, 256, 0, stream>>>(cnt_p, bsum_p, rs_p, cur_p, NBP,
                                             cnt_a, bsum_a, rs_a, cur_a);
  csr_fill2<<<(2 * NE + 255) / 256, 256, 0, stream>>>(src_ap, dst_ap, cur_p, csrc_p,
                                                      src_pa, dst_pa, cur_a, csrc_a);

  // ---- input conversion to bf16 (one launch) ----
  {
    const int n4p = NP * 256 / 4, n4a = NA * 128 / 4;
    to_bf16_2<<<(n4p + n4a + 255) / 256, 256, 0, stream>>>(x_paper, xp_bf, n4p,
                                                           x_author, xa_bf, n4a);
  }

  // ---- weight pack (single launch) ----
  {
    PackJobs J;
    const float* srcs[12] = {Wl0_ap, Wr0_ap, Wl0_pa, Wr0_pa,
                             Wl_ap, Wr_ap, Wl_pa, Wr_pa,
                             Wl_ap + 65536, Wr_ap + 65536, Wl_pa + 65536, Wr_pa + 65536};
    u16* dsts[12] = {wc0_p, wc0_p + 128 * 256, wc0_a, wc0_a + 256 * 256,
                     wc_ap, wc_ap + 65536, wc_pa, wc_pa + 65536,
                     wc_ap + 131072, wc_ap + 131072 + 65536,
                     wc_pa + 131072, wc_pa + 131072 + 65536};
    int Ks[12] = {128, 256, 256, 128, 256, 256, 256, 256, 256, 256, 256, 256};
    int off = 0;
    for (int j = 0; j < 12; ++j) {
      J.src[j] = srcs[j];
      J.dst[j] = dsts[j];
      J.K[j] = Ks[j];
      J.boff[j] = off;
      off += Ks[j] / 8;
    }
    J.boff[12] = off;
    pack_all<<<off, 256, 0, stream>>>(J);
  }
  // ---- bias combine (single launch) ----
  {
    BiasJobs J;
    const float* as[6] = {bl0_ap, bl0_pa, bl_ap, bl_ap + 256, bl_pa, bl_pa + 256};
    const float* bs[6] = {br0_ap, br0_pa, br_ap, br_ap + 256, br_pa, br_pa + 256};
    float* os[6] = {bias0_ap, bias0_pa, bias_ap, bias_ap + 256, bias_pa, bias_pa + 256};
    for (int j = 0; j < 6; ++j) { J.a[j] = as[j]; J.b[j] = bs[j]; J.o[j] = os[j]; }
    bias_all<<<6, 256, 0, stream>>>(J);
  }

  // grid: 256 rows x 128 cols per block; cg siblings adjacent logical bids,
  // XCD-chunked swizzle inside the kernel keeps them on one XCD.
  const int nbP2 = ((NP + 255) / 256) * 2;              // 782
  const int nbA2 = ((NA + 255) / 256) * 2;              // 392
  const int grid_sage = nbP2 + nbA2;                    // 1174
  const int grid_gath = (NP + NA) / 8;                  // 18750 (half-wave per node)

  // ---- layer 0 (author:128, paper:256 inputs) -> paper, author ----
  gather2<128, 256><<<grid_gath, 256, 0, stream>>>(
      xa_bf, csrc_p, rs_p, agg_p, NP, xp_bf, csrc_a, rs_a, agg_a, NA);
  sage_pipe<12><<<grid_sage, 512, 0, stream>>>(
      SideB{agg_p, xp_bf, wc0_p, bias0_ap, paper, NP, 128, 256},
      SideB{agg_a, xa_bf, wc0_a, bias0_pa, author, NA, 256, 128}, nbP2, grid_sage);

  // ---- layer 1: (paper, author) -> (paper2, author2) ----
  gather2<256, 256><<<grid_gath, 256, 0, stream>>>(
      author, csrc_p, rs_p, agg_p, NP, paper, csrc_a, rs_a, agg_a, NA);
  sage_pipe<16><<<grid_sage, 512, 0, stream>>>(
      SideB{agg_p, paper, wc_ap, bias_ap, paper2, NP, 256, 256},
      SideB{agg_a, author, wc_pa, bias_pa, author2, NA, 256, 256}, nbP2, grid_sage);

  // ---- layer 2: AUTHOR SIDE ONLY (final paper is dead code — the reference
  //      returns author @ W_out; paper from the last layer is never consumed) ----
  gather2<256, 256><<<(NA + 7) / 8, 256, 0, stream>>>(
      paper2, csrc_a, rs_a, agg_a, NA, paper2, csrc_a, rs_a, agg_a, 0);
  sage_pipe<16><<<nbA2, 512, 0, stream>>>(
      SideB{agg_a, author2, wc_pa + 131072, bias_pa + 256, author, NA, 256, 256},
      SideB{agg_a, author2, wc_pa + 131072, bias_pa + 256, author, NA, 256, 256}, 0, nbA2);

  // ---- output projection ----
  out_proj<<<(NA + 3) / 4, 256, 0, stream>>>(author, W_out, b_out, out, NA);
}